// Round 18
// baseline (88.651 us; speedup 1.0000x reference)
//
#include <hip/hip_runtime.h>
#include <math.h>

#define T_STEPS 22
#define F_IN    12
#define HID     32

typedef __attribute__((ext_vector_type(8))) short  bf16x8;
typedef __attribute__((ext_vector_type(16))) float f32x16;
typedef __attribute__((ext_vector_type(2)))  float f32x2;

union FragU { unsigned int u[4]; bf16x8 v; };

#define LOG2E    1.442695041f
#define TWOLOG2E 2.885390082f

static __device__ __forceinline__ unsigned short f2bf(float x) {
    unsigned int u = __builtin_bit_cast(unsigned int, x);
    return (unsigned short)((u + 0x7fffu + ((u >> 16) & 1u)) >> 16);
}

static __device__ __forceinline__ unsigned cvt_pk_bf16(float lo, float hi) {
    unsigned r;
    asm("v_cvt_pk_bf16_f32 %0, %1, %2" : "=v"(r) : "v"(lo), "v"(hi));
    return r;
}

static __device__ __forceinline__ float bf2f(short s_) {
    return __builtin_bit_cast(float, ((unsigned)(unsigned short)s_) << 16);
}

// ws layout (floats):
//   [0,1024)    wx_frag: [4 m][64 lane] x 8 bf16, rows prescaled; k=12 = fused bias
//   [1024,3072) wh_frag: [4 m][2 kt][64 lane] x 8 bf16, rows prescaled
//   [3072,3104) whd: [2 hi][16 j] f32 in B-frag k-order (r6/r7/r15 verified):
//               j<8 -> Whead[8*hi+j], j>=8 -> Whead[16+8*hi+(j-8)]
__global__ void prep_kernel(const float* __restrict__ Wih, const float* __restrict__ Whh,
                            const float* __restrict__ bih, const float* __restrict__ bhh,
                            const float* __restrict__ Whead, float* __restrict__ ws) {
    const int tid = threadIdx.x;  // 256
    unsigned short* wx = (unsigned short*)ws;
    unsigned short* wh = (unsigned short*)(ws + 1024);
    float* whd = ws + 3072;

    {   // wx: entry = m*64 + lane (== tid)
        int m = tid >> 6, lane = tid & 63;
        int g = 32 * m + (lane & 31);
        float scale = (m == 2) ? TWOLOG2E : -LOG2E;   // g-gate: +2log2e; i,f,o: -log2e
        int kbase = 8 * (lane >> 5);
        for (int j = 0; j < 8; ++j) {
            int k = kbase + j;
            float v = 0.0f;
            if (k < F_IN)       v = Wih[g * F_IN + k];
            else if (k == F_IN) v = bih[g] + bhh[g];
            wx[tid * 8 + j] = f2bf(scale * v);
        }
    }
    for (int e = tid; e < 4 * 2 * 64; e += 256) {
        int m = e >> 7, kt = (e >> 6) & 1, lane = e & 63;
        int g = 32 * m + (lane & 31);
        float scale = (m == 2) ? TWOLOG2E : -LOG2E;
        int kbase = 16 * kt + 8 * (lane >> 5);
        for (int j = 0; j < 8; ++j)
            wh[e * 8 + j] = f2bf(scale * Whh[g * HID + kbase + j]);
    }
    if (tid < 32) {
        int h2 = tid >> 4, j = tid & 15;
        int k = (j < 8) ? (8 * h2 + j) : (16 + 8 * h2 + (j - 8));
        whd[tid] = Whead[k];
    }
}

// The one untested config cell: LEAN 32x32 stream at the 4-wave tier.
// r15 minus zc: per-step acc zero-init keeps AGPR at exactly 64;
// VGPR ~60 -> total ~124 <= 128 -> 4 waves/SIMD, whole grid resident in one
// round. LDS weights (opaque-zero LICM block, x loads pipeline), 1-step x
// prefetch, inline bf16 h-pack, no sched_group_barriers.
__global__ void __launch_bounds__(256, 2)
lstm_kernel(const float* __restrict__ x, const float* __restrict__ ws,
            const float* __restrict__ bheadp, float* __restrict__ out, int B) {
    const int tid  = threadIdx.x;
    const int lane = tid & 63;
    const int wave = tid >> 6;
    const int col  = lane & 31;
    const int hi   = lane >> 5;
    int b = blockIdx.x * 128 + wave * 32 + col;
    const bool valid = (b < B);
    if (b >= B) b = B - 1;          // clamp; all threads reach the barrier

    __shared__ float wlds[3072];    // 12 KB: wx [0,1024), wh [1024,3072)
#pragma unroll
    for (int i = 0; i < 3; ++i)
        ((float4*)wlds)[tid + i * 256] = ((const float4*)ws)[tid + i * 256];
    __syncthreads();

    // lo lanes read x[0..3],x[4..7]; hi lanes read x[8..11] (2nd load unused there)
    const float* xb1 = x + (size_t)b * (T_STEPS * F_IN) + (hi ? 8 : 0);
    const float* xb2 = x + (size_t)b * (T_STEPS * F_IN) + (hi ? 8 : 4);

    f32x2 c2[8];
#pragma unroll
    for (int p = 0; p < 8; ++p) c2[p] = (f32x2){0.f, 0.f};
    bf16x8 hf0, hf1;
#pragma unroll
    for (int j = 0; j < 8; ++j) { hf0[j] = 0; hf1[j] = 0; }

    const f32x2 one2 = {1.0f, 1.0f};

    float4 va = *(const float4*)(xb1);
    float4 vb = *(const float4*)(xb2);

#pragma unroll 1
    for (int t = 0; t < T_STEPS; ++t) {
        // opaque zero blocks LICM of the 12 weight ds_reads without a memory
        // clobber (x loads still pipeline; r13/r14/r15-proven).
        int zr = 0;
        asm("" : "+v"(zr));
        const bf16x8* wx_l = ((const bf16x8*)wlds) + zr;          // [4][64]
        const bf16x8* wh_l = ((const bf16x8*)wlds) + 256 + zr;    // [4][2][64]

        // prefetch next step's x (consumed a full iteration later)
        const int tn = (t + 1 < T_STEPS) ? t + 1 : t;
        float4 na = *(const float4*)(xb1 + tn * F_IN);
        float4 nb = *(const float4*)(xb2 + tn * F_IN);

        FragU xf;
        xf.u[0] = cvt_pk_bf16(va.x, va.y);
        xf.u[1] = cvt_pk_bf16(va.z, va.w);
        unsigned w2 = cvt_pk_bf16(vb.x, vb.y);
        unsigned w3 = cvt_pk_bf16(vb.z, vb.w);
        xf.u[2] = hi ? 0x00003f80u : w2;   // k=12 -> 1.0 (fused bias feature)
        xf.u[3] = hi ? 0u : w3;

        f32x16 a0, a1, a2, a3;   // per-step zero init: keeps AGPR total at 64
#pragma unroll
        for (int q = 0; q < 16; ++q) { a0[q] = 0.f; a1[q] = 0.f; a2[q] = 0.f; a3[q] = 0.f; }

        a0 = __builtin_amdgcn_mfma_f32_32x32x16_bf16(wx_l[0 * 64 + lane], xf.v, a0, 0, 0, 0);
        a1 = __builtin_amdgcn_mfma_f32_32x32x16_bf16(wx_l[1 * 64 + lane], xf.v, a1, 0, 0, 0);
        a2 = __builtin_amdgcn_mfma_f32_32x32x16_bf16(wx_l[2 * 64 + lane], xf.v, a2, 0, 0, 0);
        a3 = __builtin_amdgcn_mfma_f32_32x32x16_bf16(wx_l[3 * 64 + lane], xf.v, a3, 0, 0, 0);
        a0 = __builtin_amdgcn_mfma_f32_32x32x16_bf16(wh_l[(0 * 2 + 0) * 64 + lane], hf0, a0, 0, 0, 0);
        a1 = __builtin_amdgcn_mfma_f32_32x32x16_bf16(wh_l[(1 * 2 + 0) * 64 + lane], hf0, a1, 0, 0, 0);
        a2 = __builtin_amdgcn_mfma_f32_32x32x16_bf16(wh_l[(2 * 2 + 0) * 64 + lane], hf0, a2, 0, 0, 0);
        a3 = __builtin_amdgcn_mfma_f32_32x32x16_bf16(wh_l[(3 * 2 + 0) * 64 + lane], hf0, a3, 0, 0, 0);
        a0 = __builtin_amdgcn_mfma_f32_32x32x16_bf16(wh_l[(0 * 2 + 1) * 64 + lane], hf1, a0, 0, 0, 0);
        a1 = __builtin_amdgcn_mfma_f32_32x32x16_bf16(wh_l[(1 * 2 + 1) * 64 + lane], hf1, a1, 0, 0, 0);
        a2 = __builtin_amdgcn_mfma_f32_32x32x16_bf16(wh_l[(2 * 2 + 1) * 64 + lane], hf1, a2, 0, 0, 0);
        a3 = __builtin_amdgcn_mfma_f32_32x32x16_bf16(wh_l[(3 * 2 + 1) * 64 + lane], hf1, a3, 0, 0, 0);

        // Fused-rcp cell (7 trans/unit), f32x2-packed; h packed to bf16 inline.
        unsigned P[8];
#pragma unroll
        for (int p = 0; p < 8; ++p) {
            const int q0 = 2 * p, q1 = 2 * p + 1;
            f32x2 ei = {__builtin_amdgcn_exp2f(a0[q0]), __builtin_amdgcn_exp2f(a0[q1])};
            f32x2 ef = {__builtin_amdgcn_exp2f(a1[q0]), __builtin_amdgcn_exp2f(a1[q1])};
            f32x2 eg = {__builtin_amdgcn_exp2f(a2[q0]), __builtin_amdgcn_exp2f(a2[q1])};
            f32x2 eo = {__builtin_amdgcn_exp2f(a3[q0]), __builtin_amdgcn_exp2f(a3[q1])};
            f32x2 A  = (one2 + ei) * (one2 + eg);
            f32x2 F  = one2 + ef;
            f32x2 FA = F * A;
            f32x2 r1 = {__builtin_amdgcn_rcpf(FA.x), __builtin_amdgcn_rcpf(FA.y)};
            f32x2 t2 = eg * (f32x2){TWOLOG2E, TWOLOG2E} - (f32x2){TWOLOG2E, TWOLOG2E};
            f32x2 num = t2 * F + c2[p] * A;
            c2[p] = num * r1;
            f32x2 ec = {__builtin_amdgcn_exp2f(c2[p].x), __builtin_amdgcn_exp2f(c2[p].y)};
            f32x2 r2in = (one2 + eo) * (one2 + ec);
            f32x2 r2 = {__builtin_amdgcn_rcpf(r2in.x), __builtin_amdgcn_rcpf(r2in.y)};
            f32x2 hv = (ec - one2) * r2;
            P[p] = cvt_pk_bf16(hv.x, hv.y);
        }

        asm("v_permlane32_swap_b32 %0, %1" : "+v"(P[0]), "+v"(P[2]));
        asm("v_permlane32_swap_b32 %0, %1" : "+v"(P[1]), "+v"(P[3]));
        asm("v_permlane32_swap_b32 %0, %1" : "+v"(P[4]), "+v"(P[6]));
        asm("v_permlane32_swap_b32 %0, %1" : "+v"(P[5]), "+v"(P[7]));
        FragU h0; h0.u[0] = P[0]; h0.u[1] = P[1]; h0.u[2] = P[2]; h0.u[3] = P[3];
        FragU h1; h1.u[0] = P[4]; h1.u[1] = P[5]; h1.u[2] = P[6]; h1.u[3] = P[7];
        hf0 = h0.v;
        hf1 = h1.v;

        va = na; vb = nb;
    }

    // head from bf16 B-frags (r6/r7/r15-verified): hf0[j]=h[8hi+j], hf1[j]=h[16+8hi+j]
    const float* whd = ws + 3072 + hi * 16;
    float y = 0.0f;
#pragma unroll
    for (int j = 0; j < 8; ++j) {
        y = fmaf(bf2f(hf0[j]), whd[j],     y);
        y = fmaf(bf2f(hf1[j]), whd[8 + j], y);
    }
    y += __shfl_xor(y, 32, 64);
    y += bheadp[0];
    float sp = fmaxf(y, 0.0f) + log1pf(expf(-fabsf(y)));
    if (valid && hi == 0) out[b] = sp;
}

extern "C" void kernel_launch(void* const* d_in, const int* in_sizes, int n_in,
                              void* d_out, int out_size, void* d_ws, size_t ws_size,
                              hipStream_t stream) {
    const float* x     = (const float*)d_in[0];
    const float* Wih   = (const float*)d_in[1];
    const float* Whh   = (const float*)d_in[2];
    const float* bih   = (const float*)d_in[3];
    const float* bhh   = (const float*)d_in[4];
    const float* Whead = (const float*)d_in[5];
    const float* bhead = (const float*)d_in[6];
    float* out = (float*)d_out;
    float* ws  = (float*)d_ws;

    const int B = in_sizes[0] / (T_STEPS * F_IN);
    const int blocks = (B + 127) / 128;

    hipLaunchKernelGGL(prep_kernel, dim3(1), dim3(256), 0, stream,
                       Wih, Whh, bih, bhh, Whead, ws);
    hipLaunchKernelGGL(lstm_kernel, dim3(blocks), dim3(256), 0, stream,
                       x, ws, bhead, out, B);
}

// Round 19
// 87.397 us; speedup vs baseline: 1.0144x; 1.0144x over previous
//
#include <hip/hip_runtime.h>
#include <math.h>

#define T_STEPS 22
#define F_IN    12
#define HID     32

typedef __attribute__((ext_vector_type(8))) short  bf16x8;
typedef __attribute__((ext_vector_type(16))) float f32x16;
typedef __attribute__((ext_vector_type(2)))  float f32x2;

union FragU { unsigned int u[4]; bf16x8 v; };

#define LOG2E    1.442695041f
#define TWOLOG2E 2.885390082f

static __device__ __forceinline__ unsigned short f2bf(float x) {
    unsigned int u = __builtin_bit_cast(unsigned int, x);
    return (unsigned short)((u + 0x7fffu + ((u >> 16) & 1u)) >> 16);
}

static __device__ __forceinline__ unsigned cvt_pk_bf16(float lo, float hi) {
    unsigned r;
    asm("v_cvt_pk_bf16_f32 %0, %1, %2" : "=v"(r) : "v"(lo), "v"(hi));
    return r;
}

static __device__ __forceinline__ float bf2f(short s_) {
    return __builtin_bit_cast(float, ((unsigned)(unsigned short)s_) << 16);
}

// ws layout (floats):
//   [0,1024)    wx_frag: [4 m][64 lane] x 8 bf16, rows prescaled; k=12 = fused bias
//   [1024,3072) wh_frag: [4 m][2 kt][64 lane] x 8 bf16, rows prescaled
//   [3072,3104) whd: [2 hi][16 j] f32 in B-frag k-order (r6/r7/r15 verified):
//               j<8 -> Whead[8*hi+j], j>=8 -> Whead[16+8*hi+(j-8)]
__global__ void prep_kernel(const float* __restrict__ Wih, const float* __restrict__ Whh,
                            const float* __restrict__ bih, const float* __restrict__ bhh,
                            const float* __restrict__ Whead, float* __restrict__ ws) {
    const int tid = threadIdx.x;  // 256
    unsigned short* wx = (unsigned short*)ws;
    unsigned short* wh = (unsigned short*)(ws + 1024);
    float* whd = ws + 3072;

    {   // wx: entry = m*64 + lane (== tid)
        int m = tid >> 6, lane = tid & 63;
        int g = 32 * m + (lane & 31);
        float scale = (m == 2) ? TWOLOG2E : -LOG2E;   // g-gate: +2log2e; i,f,o: -log2e
        int kbase = 8 * (lane >> 5);
        for (int j = 0; j < 8; ++j) {
            int k = kbase + j;
            float v = 0.0f;
            if (k < F_IN)       v = Wih[g * F_IN + k];
            else if (k == F_IN) v = bih[g] + bhh[g];
            wx[tid * 8 + j] = f2bf(scale * v);
        }
    }
    for (int e = tid; e < 4 * 2 * 64; e += 256) {
        int m = e >> 7, kt = (e >> 6) & 1, lane = e & 63;
        int g = 32 * m + (lane & 31);
        float scale = (m == 2) ? TWOLOG2E : -LOG2E;
        int kbase = 16 * kt + 8 * (lane >> 5);
        for (int j = 0; j < 8; ++j)
            wh[e * 8 + j] = f2bf(scale * Whh[g * HID + kbase + j]);
    }
    if (tid < 32) {
        int h2 = tid >> 4, j = tid & 15;
        int k = (j < 8) ? (8 * h2 + j) : (16 + 8 * h2 + (j - 8));
        whd[tid] = Whead[k];
    }
}

// Lean 32x32 stream, minimal VGPR for a DECISIVE 4-wave-tier landing:
// r18 minus x-prefetch (loads in body; 4 resident waves cover L3 latency).
// Target ~44-48 VGPR + 64 AGPR (accum_offset 48+64=112) << 128.
__global__ void __launch_bounds__(256, 2)
lstm_kernel(const float* __restrict__ x, const float* __restrict__ ws,
            const float* __restrict__ bheadp, float* __restrict__ out, int B) {
    const int tid  = threadIdx.x;
    const int lane = tid & 63;
    const int wave = tid >> 6;
    const int col  = lane & 31;
    const int hi   = lane >> 5;
    int b = blockIdx.x * 128 + wave * 32 + col;
    const bool valid = (b < B);
    if (b >= B) b = B - 1;          // clamp; all threads reach the barrier

    __shared__ float wlds[3072];    // 12 KB: wx [0,1024), wh [1024,3072)
#pragma unroll
    for (int i = 0; i < 3; ++i)
        ((float4*)wlds)[tid + i * 256] = ((const float4*)ws)[tid + i * 256];
    __syncthreads();

    // lo lanes read x[0..3],x[4..7]; hi lanes read x[8..11] (2nd load unused there)
    const float* xb1 = x + (size_t)b * (T_STEPS * F_IN) + (hi ? 8 : 0);
    const float* xb2 = x + (size_t)b * (T_STEPS * F_IN) + (hi ? 8 : 4);

    f32x2 c2[8];
#pragma unroll
    for (int p = 0; p < 8; ++p) c2[p] = (f32x2){0.f, 0.f};
    bf16x8 hf0, hf1;
#pragma unroll
    for (int j = 0; j < 8; ++j) { hf0[j] = 0; hf1[j] = 0; }

    const f32x2 one2 = {1.0f, 1.0f};

#pragma unroll 1
    for (int t = 0; t < T_STEPS; ++t) {
        // opaque zero blocks LICM of the 12 weight ds_reads without a memory
        // clobber (x loads schedule freely; r13-r15-proven).
        int zr = 0;
        asm("" : "+v"(zr));
        const bf16x8* wx_l = ((const bf16x8*)wlds) + zr;          // [4][64]
        const bf16x8* wh_l = ((const bf16x8*)wlds) + 256 + zr;    // [4][2][64]

        float4 va = *(const float4*)(xb1 + t * F_IN);
        float4 vb = *(const float4*)(xb2 + t * F_IN);

        FragU xf;
        xf.u[0] = cvt_pk_bf16(va.x, va.y);
        xf.u[1] = cvt_pk_bf16(va.z, va.w);
        unsigned w2 = cvt_pk_bf16(vb.x, vb.y);
        unsigned w3 = cvt_pk_bf16(vb.z, vb.w);
        xf.u[2] = hi ? 0x00003f80u : w2;   // k=12 -> 1.0 (fused bias feature)
        xf.u[3] = hi ? 0u : w3;

        f32x16 a0, a1, a2, a3;   // per-step zero init: AGPR total stays 64
#pragma unroll
        for (int q = 0; q < 16; ++q) { a0[q] = 0.f; a1[q] = 0.f; a2[q] = 0.f; a3[q] = 0.f; }

        a0 = __builtin_amdgcn_mfma_f32_32x32x16_bf16(wx_l[0 * 64 + lane], xf.v, a0, 0, 0, 0);
        a1 = __builtin_amdgcn_mfma_f32_32x32x16_bf16(wx_l[1 * 64 + lane], xf.v, a1, 0, 0, 0);
        a2 = __builtin_amdgcn_mfma_f32_32x32x16_bf16(wx_l[2 * 64 + lane], xf.v, a2, 0, 0, 0);
        a3 = __builtin_amdgcn_mfma_f32_32x32x16_bf16(wx_l[3 * 64 + lane], xf.v, a3, 0, 0, 0);
        a0 = __builtin_amdgcn_mfma_f32_32x32x16_bf16(wh_l[(0 * 2 + 0) * 64 + lane], hf0, a0, 0, 0, 0);
        a1 = __builtin_amdgcn_mfma_f32_32x32x16_bf16(wh_l[(1 * 2 + 0) * 64 + lane], hf0, a1, 0, 0, 0);
        a2 = __builtin_amdgcn_mfma_f32_32x32x16_bf16(wh_l[(2 * 2 + 0) * 64 + lane], hf0, a2, 0, 0, 0);
        a3 = __builtin_amdgcn_mfma_f32_32x32x16_bf16(wh_l[(3 * 2 + 0) * 64 + lane], hf0, a3, 0, 0, 0);
        a0 = __builtin_amdgcn_mfma_f32_32x32x16_bf16(wh_l[(0 * 2 + 1) * 64 + lane], hf1, a0, 0, 0, 0);
        a1 = __builtin_amdgcn_mfma_f32_32x32x16_bf16(wh_l[(1 * 2 + 1) * 64 + lane], hf1, a1, 0, 0, 0);
        a2 = __builtin_amdgcn_mfma_f32_32x32x16_bf16(wh_l[(2 * 2 + 1) * 64 + lane], hf1, a2, 0, 0, 0);
        a3 = __builtin_amdgcn_mfma_f32_32x32x16_bf16(wh_l[(3 * 2 + 1) * 64 + lane], hf1, a3, 0, 0, 0);

        // Fused-rcp cell (7 trans/unit), f32x2-packed; h packed to bf16 inline.
        unsigned P[8];
#pragma unroll
        for (int p = 0; p < 8; ++p) {
            const int q0 = 2 * p, q1 = 2 * p + 1;
            f32x2 ei = {__builtin_amdgcn_exp2f(a0[q0]), __builtin_amdgcn_exp2f(a0[q1])};
            f32x2 ef = {__builtin_amdgcn_exp2f(a1[q0]), __builtin_amdgcn_exp2f(a1[q1])};
            f32x2 eg = {__builtin_amdgcn_exp2f(a2[q0]), __builtin_amdgcn_exp2f(a2[q1])};
            f32x2 eo = {__builtin_amdgcn_exp2f(a3[q0]), __builtin_amdgcn_exp2f(a3[q1])};
            f32x2 A  = (one2 + ei) * (one2 + eg);
            f32x2 F  = one2 + ef;
            f32x2 FA = F * A;
            f32x2 r1 = {__builtin_amdgcn_rcpf(FA.x), __builtin_amdgcn_rcpf(FA.y)};
            f32x2 t2 = eg * (f32x2){TWOLOG2E, TWOLOG2E} - (f32x2){TWOLOG2E, TWOLOG2E};
            f32x2 num = t2 * F + c2[p] * A;
            c2[p] = num * r1;
            f32x2 ec = {__builtin_amdgcn_exp2f(c2[p].x), __builtin_amdgcn_exp2f(c2[p].y)};
            f32x2 r2in = (one2 + eo) * (one2 + ec);
            f32x2 r2 = {__builtin_amdgcn_rcpf(r2in.x), __builtin_amdgcn_rcpf(r2in.y)};
            f32x2 hv = (ec - one2) * r2;
            P[p] = cvt_pk_bf16(hv.x, hv.y);
        }

        asm("v_permlane32_swap_b32 %0, %1" : "+v"(P[0]), "+v"(P[2]));
        asm("v_permlane32_swap_b32 %0, %1" : "+v"(P[1]), "+v"(P[3]));
        asm("v_permlane32_swap_b32 %0, %1" : "+v"(P[4]), "+v"(P[6]));
        asm("v_permlane32_swap_b32 %0, %1" : "+v"(P[5]), "+v"(P[7]));
        FragU h0; h0.u[0] = P[0]; h0.u[1] = P[1]; h0.u[2] = P[2]; h0.u[3] = P[3];
        FragU h1; h1.u[0] = P[4]; h1.u[1] = P[5]; h1.u[2] = P[6]; h1.u[3] = P[7];
        hf0 = h0.v;
        hf1 = h1.v;
    }

    // head from bf16 B-frags (r6/r7/r15-verified): hf0[j]=h[8hi+j], hf1[j]=h[16+8hi+j]
    const float* whd = ws + 3072 + hi * 16;
    float y = 0.0f;
#pragma unroll
    for (int j = 0; j < 8; ++j) {
        y = fmaf(bf2f(hf0[j]), whd[j],     y);
        y = fmaf(bf2f(hf1[j]), whd[8 + j], y);
    }
    y += __shfl_xor(y, 32, 64);
    y += bheadp[0];
    float sp = fmaxf(y, 0.0f) + log1pf(expf(-fabsf(y)));
    if (valid && hi == 0) out[b] = sp;
}

extern "C" void kernel_launch(void* const* d_in, const int* in_sizes, int n_in,
                              void* d_out, int out_size, void* d_ws, size_t ws_size,
                              hipStream_t stream) {
    const float* x     = (const float*)d_in[0];
    const float* Wih   = (const float*)d_in[1];
    const float* Whh   = (const float*)d_in[2];
    const float* bih   = (const float*)d_in[3];
    const float* bhh   = (const float*)d_in[4];
    const float* Whead = (const float*)d_in[5];
    const float* bhead = (const float*)d_in[6];
    float* out = (float*)d_out;
    float* ws  = (float*)d_ws;

    const int B = in_sizes[0] / (T_STEPS * F_IN);
    const int blocks = (B + 127) / 128;

    hipLaunchKernelGGL(prep_kernel, dim3(1), dim3(256), 0, stream,
                       Wih, Whh, bih, bhh, Whead, ws);
    hipLaunchKernelGGL(lstm_kernel, dim3(blocks), dim3(256), 0, stream,
                       x, ws, bhead, out, B);
}

// Round 20
// 85.832 us; speedup vs baseline: 1.0328x; 1.0182x over previous
//
#include <hip/hip_runtime.h>
#include <math.h>

#define T_STEPS 22
#define F_IN    12
#define HID     32

typedef __attribute__((ext_vector_type(8))) short  bf16x8;
typedef __attribute__((ext_vector_type(16))) float f32x16;
typedef __attribute__((ext_vector_type(2)))  float f32x2;

union FragU { unsigned int u[4]; bf16x8 v; };

#define LOG2E    1.442695041f
#define TWOLOG2E 2.885390082f

static __device__ __forceinline__ unsigned short f2bf(float x) {
    unsigned int u = __builtin_bit_cast(unsigned int, x);
    return (unsigned short)((u + 0x7fffu + ((u >> 16) & 1u)) >> 16);
}

static __device__ __forceinline__ unsigned cvt_pk_bf16(float lo, float hi) {
    unsigned r;
    asm("v_cvt_pk_bf16_f32 %0, %1, %2" : "=v"(r) : "v"(lo), "v"(hi));
    return r;
}

// ws layout (floats):
//   [0,1024)    wx_frag: [4 m][64 lane] x 8 bf16, rows prescaled; k=12 = fused bias
//   [1024,3072) wh_frag: [4 m][2 kt][64 lane] x 8 bf16, rows prescaled
//   [3072,3104) whead:   [2 hi][16 q] f32 permuted to C-layout rows
__global__ void prep_kernel(const float* __restrict__ Wih, const float* __restrict__ Whh,
                            const float* __restrict__ bih, const float* __restrict__ bhh,
                            const float* __restrict__ Whead, float* __restrict__ ws) {
    const int tid = threadIdx.x;  // 256
    unsigned short* wx = (unsigned short*)ws;
    unsigned short* wh = (unsigned short*)(ws + 1024);
    float* whd = ws + 3072;

    {   // wx: entry = m*64 + lane (== tid)
        int m = tid >> 6, lane = tid & 63;
        int g = 32 * m + (lane & 31);
        float scale = (m == 2) ? TWOLOG2E : -LOG2E;   // g-gate: +2log2e; i,f,o: -log2e
        int kbase = 8 * (lane >> 5);
        for (int j = 0; j < 8; ++j) {
            int k = kbase + j;
            float v = 0.0f;
            if (k < F_IN)       v = Wih[g * F_IN + k];
            else if (k == F_IN) v = bih[g] + bhh[g];
            wx[tid * 8 + j] = f2bf(scale * v);
        }
    }
    for (int e = tid; e < 4 * 2 * 64; e += 256) {
        int m = e >> 7, kt = (e >> 6) & 1, lane = e & 63;
        int g = 32 * m + (lane & 31);
        float scale = (m == 2) ? TWOLOG2E : -LOG2E;
        int kbase = 16 * kt + 8 * (lane >> 5);
        for (int j = 0; j < 8; ++j)
            wh[e * 8 + j] = f2bf(scale * Whh[g * HID + kbase + j]);
    }
    if (tid < 32) {
        int hi = tid >> 4, q = tid & 15;
        int j = (q & 3) + 8 * (q >> 2) + 4 * hi;
        whd[tid] = Whead[j];
    }
}

// Session-best configuration (r17, 85.47 us): 32x32 MFMA, register weights,
// fused-rcp f32x2 cell (7 trans/unit), cvt_pk+permlane repack, zc hoist,
// 1-step x prefetch, (256,2). 2 waves/SIMD; plateau is wave-phase-bound.
__global__ void __launch_bounds__(256, 2)
lstm_kernel(const float* __restrict__ x, const float* __restrict__ ws,
            const float* __restrict__ bheadp, float* __restrict__ out, int B) {
    const int lane = threadIdx.x & 63;
    const int wave = threadIdx.x >> 6;
    const int col  = lane & 31;
    const int hi   = lane >> 5;
    int b = blockIdx.x * 128 + wave * 32 + col;
    const bool valid = (b < B);
    if (b >= B) b = B - 1;

    const bf16x8* wxp = (const bf16x8*)ws;
    const bf16x8* whp = (const bf16x8*)(ws + 1024);
    bf16x8 wxf[4], whf[4][2];
#pragma unroll
    for (int m = 0; m < 4; ++m) wxf[m] = wxp[m * 64 + lane];
#pragma unroll
    for (int m = 0; m < 4; ++m)
#pragma unroll
        for (int kt = 0; kt < 2; ++kt) whf[m][kt] = whp[(m * 2 + kt) * 64 + lane];

    // lo lanes read x[0..3],x[4..7]; hi lanes read x[8..11] (2nd load unused there)
    const float* xb1 = x + (size_t)b * (T_STEPS * F_IN) + (hi ? 8 : 0);
    const float* xb2 = x + (size_t)b * (T_STEPS * F_IN) + (hi ? 8 : 4);

    f32x2 c2[8], hv2[8];
#pragma unroll
    for (int p = 0; p < 8; ++p) { c2[p] = (f32x2){0.f, 0.f}; hv2[p] = (f32x2){0.f, 0.f}; }
    bf16x8 hf0, hf1;
#pragma unroll
    for (int j = 0; j < 8; ++j) { hf0[j] = 0; hf1[j] = 0; }

    f32x16 zc;   // hoisted zero C-in: removes 64 acc-zero writes per step
#pragma unroll
    for (int q = 0; q < 16; ++q) zc[q] = 0.0f;

    const f32x2 one2 = {1.0f, 1.0f};

    float4 va = *(const float4*)(xb1);
    float4 vb = *(const float4*)(xb2);

    for (int t = 0; t < T_STEPS; ++t) {
        // prefetch next step's x (consumed a full iteration later; clamp tail)
        const int tn = (t + 1 < T_STEPS) ? t + 1 : t;
        float4 na = *(const float4*)(xb1 + tn * F_IN);
        float4 nb = *(const float4*)(xb2 + tn * F_IN);

        FragU xf;
        xf.u[0] = cvt_pk_bf16(va.x, va.y);
        xf.u[1] = cvt_pk_bf16(va.z, va.w);
        unsigned w2 = cvt_pk_bf16(vb.x, vb.y);
        unsigned w3 = cvt_pk_bf16(vb.z, vb.w);
        xf.u[2] = hi ? 0x00003f80u : w2;   // k=12 -> 1.0 (fused bias feature)
        xf.u[3] = hi ? 0u : w3;

        f32x16 a0, a1, a2, a3;
        a0 = __builtin_amdgcn_mfma_f32_32x32x16_bf16(wxf[0], xf.v, zc, 0, 0, 0);
        a1 = __builtin_amdgcn_mfma_f32_32x32x16_bf16(wxf[1], xf.v, zc, 0, 0, 0);
        a2 = __builtin_amdgcn_mfma_f32_32x32x16_bf16(wxf[2], xf.v, zc, 0, 0, 0);
        a3 = __builtin_amdgcn_mfma_f32_32x32x16_bf16(wxf[3], xf.v, zc, 0, 0, 0);
        a0 = __builtin_amdgcn_mfma_f32_32x32x16_bf16(whf[0][0], hf0, a0, 0, 0, 0);
        a1 = __builtin_amdgcn_mfma_f32_32x32x16_bf16(whf[1][0], hf0, a1, 0, 0, 0);
        a2 = __builtin_amdgcn_mfma_f32_32x32x16_bf16(whf[2][0], hf0, a2, 0, 0, 0);
        a3 = __builtin_amdgcn_mfma_f32_32x32x16_bf16(whf[3][0], hf0, a3, 0, 0, 0);
        a0 = __builtin_amdgcn_mfma_f32_32x32x16_bf16(whf[0][1], hf1, a0, 0, 0, 0);
        a1 = __builtin_amdgcn_mfma_f32_32x32x16_bf16(whf[1][1], hf1, a1, 0, 0, 0);
        a2 = __builtin_amdgcn_mfma_f32_32x32x16_bf16(whf[2][1], hf1, a2, 0, 0, 0);
        a3 = __builtin_amdgcn_mfma_f32_32x32x16_bf16(whf[3][1], hf1, a3, 0, 0, 0);

        // Fused-rcp cell, f32x2-packed full-rate math, scalar trans (7/unit).
        #pragma unroll
        for (int p = 0; p < 8; ++p) {
            const int q0 = 2 * p, q1 = 2 * p + 1;
            f32x2 ei = {__builtin_amdgcn_exp2f(a0[q0]), __builtin_amdgcn_exp2f(a0[q1])};
            f32x2 ef = {__builtin_amdgcn_exp2f(a1[q0]), __builtin_amdgcn_exp2f(a1[q1])};
            f32x2 eg = {__builtin_amdgcn_exp2f(a2[q0]), __builtin_amdgcn_exp2f(a2[q1])};
            f32x2 eo = {__builtin_amdgcn_exp2f(a3[q0]), __builtin_amdgcn_exp2f(a3[q1])};
            f32x2 A  = (one2 + ei) * (one2 + eg);
            f32x2 F  = one2 + ef;
            f32x2 FA = F * A;
            f32x2 r1 = {__builtin_amdgcn_rcpf(FA.x), __builtin_amdgcn_rcpf(FA.y)};
            f32x2 t2 = eg * (f32x2){TWOLOG2E, TWOLOG2E} - (f32x2){TWOLOG2E, TWOLOG2E};
            f32x2 num = t2 * F + c2[p] * A;
            c2[p] = num * r1;
            f32x2 ec = {__builtin_amdgcn_exp2f(c2[p].x), __builtin_amdgcn_exp2f(c2[p].y)};
            f32x2 r2in = (one2 + eo) * (one2 + ec);
            f32x2 r2 = {__builtin_amdgcn_rcpf(r2in.x), __builtin_amdgcn_rcpf(r2in.y)};
            hv2[p] = (ec - one2) * r2;
        }

        // repack h (C-layout) -> next B-fragments
        unsigned P0 = cvt_pk_bf16(hv2[0].x, hv2[0].y);
        unsigned P1 = cvt_pk_bf16(hv2[1].x, hv2[1].y);
        unsigned P2 = cvt_pk_bf16(hv2[2].x, hv2[2].y);
        unsigned P3 = cvt_pk_bf16(hv2[3].x, hv2[3].y);
        unsigned P4 = cvt_pk_bf16(hv2[4].x, hv2[4].y);
        unsigned P5 = cvt_pk_bf16(hv2[5].x, hv2[5].y);
        unsigned P6 = cvt_pk_bf16(hv2[6].x, hv2[6].y);
        unsigned P7 = cvt_pk_bf16(hv2[7].x, hv2[7].y);
        asm("v_permlane32_swap_b32 %0, %1" : "+v"(P0), "+v"(P2));
        asm("v_permlane32_swap_b32 %0, %1" : "+v"(P1), "+v"(P3));
        asm("v_permlane32_swap_b32 %0, %1" : "+v"(P4), "+v"(P6));
        asm("v_permlane32_swap_b32 %0, %1" : "+v"(P5), "+v"(P7));
        FragU h0; h0.u[0] = P0; h0.u[1] = P1; h0.u[2] = P2; h0.u[3] = P3;
        FragU h1; h1.u[0] = P4; h1.u[1] = P5; h1.u[2] = P6; h1.u[3] = P7;
        hf0 = h0.v;
        hf1 = h1.v;

        va = na; vb = nb;
    }

    // head: y = h . Whead + bhead ; softplus
    const float* whd = ws + 3072 + hi * 16;
    float y = 0.0f;
#pragma unroll
    for (int p = 0; p < 8; ++p) {
        y = fmaf(hv2[p].x, whd[2 * p],     y);
        y = fmaf(hv2[p].y, whd[2 * p + 1], y);
    }
    y += __shfl_xor(y, 32, 64);
    y += bheadp[0];
    float sp = fmaxf(y, 0.0f) + log1pf(expf(-fabsf(y)));
    if (valid && hi == 0) out[b] = sp;
}

extern "C" void kernel_launch(void* const* d_in, const int* in_sizes, int n_in,
                              void* d_out, int out_size, void* d_ws, size_t ws_size,
                              hipStream_t stream) {
    const float* x     = (const float*)d_in[0];
    const float* Wih   = (const float*)d_in[1];
    const float* Whh   = (const float*)d_in[2];
    const float* bih   = (const float*)d_in[3];
    const float* bhh   = (const float*)d_in[4];
    const float* Whead = (const float*)d_in[5];
    const float* bhead = (const float*)d_in[6];
    float* out = (float*)d_out;
    float* ws  = (float*)d_ws;

    const int B = in_sizes[0] / (T_STEPS * F_IN);
    const int blocks = (B + 127) / 128;

    hipLaunchKernelGGL(prep_kernel, dim3(1), dim3(256), 0, stream,
                       Wih, Whh, bih, bhh, Whead, ws);
    hipLaunchKernelGGL(lstm_kernel, dim3(blocks), dim3(256), 0, stream,
                       x, ws, bhead, out, B);
}